// Round 1
// baseline (710.380 us; speedup 1.0000x reference)
//
#include <hip/hip_runtime.h>
#include <stdint.h>

// Problem constants (from reference): x (N,L,D), attention over sample axis N.
#define NS 256
#define LS 512
#define DS 256
#define HS 8
#define HD 32
#define SCALE 0.17677669529663687f  // hd^-0.5

typedef __attribute__((ext_vector_type(4))) float f32x4;
typedef __attribute__((ext_vector_type(8))) __bf16 bf16x8;
typedef __attribute__((ext_vector_type(8))) unsigned short ushort8;

// fp32 -> bf16 round-to-nearest-even (finite inputs only; avoids hip_bf16 header deps)
static __device__ __forceinline__ unsigned short f2bf(float f) {
  unsigned int u = __builtin_bit_cast(unsigned int, f);
  u += 0x7fffu + ((u >> 16) & 1u);
  return (unsigned short)(u >> 16);
}

// async global->LDS, 16B per lane. LDS dest is wave-uniform base + lane*16.
static __device__ __forceinline__ void gld16(const void* g, void* l) {
  __builtin_amdgcn_global_load_lds((const __attribute__((address_space(1))) void*)g,
                                   (__attribute__((address_space(3))) void*)l, 16, 0, 0);
}

static __device__ __forceinline__ f32x4 mfma16(bf16x8 a, bf16x8 b, f32x4 c) {
  return __builtin_amdgcn_mfma_f32_16x16x32_bf16(a, b, c, 0, 0, 0);
}

// ---------------- fp32 -> bf16 conversion (vectorized, grid-stride) ----------------
__global__ void k_cvt(const float* __restrict__ in, unsigned short* __restrict__ out, int n) {
  int stride = gridDim.x * blockDim.x;
  for (int i = blockIdx.x * blockDim.x + threadIdx.x; i * 8 < n; i += stride) {
    int b = i * 8;
    float4 a0 = *(const float4*)(in + b);
    float4 a1 = *(const float4*)(in + b + 4);
    ushort8 o;
    o[0] = f2bf(a0.x); o[1] = f2bf(a0.y); o[2] = f2bf(a0.z); o[3] = f2bf(a0.w);
    o[4] = f2bf(a1.x); o[5] = f2bf(a1.y); o[6] = f2bf(a1.z); o[7] = f2bf(a1.w);
    *(ushort8*)(out + b) = o;
  }
}

// ---------------- QKV projection GEMM ----------------
// C[r][e] = sum_d x_row(r)[d] * w_qkv[e][d], r = l*NS + n  (so each 128-row tile has
// a single l and 128 consecutive n -> epilogue writes contiguous [h][l][n][hd] runs).
// m97 structure: 128x128 tile, BK=64, 4 waves (2x2), global_load_lds dwordx4 staging.
__global__ __launch_bounds__(256) void k_qkv(const unsigned short* __restrict__ xb,
                                             const unsigned short* __restrict__ wq,
                                             unsigned short* __restrict__ qkv) {
  __shared__ unsigned short As[128 * 64];
  __shared__ unsigned short Bs[128 * 64];
  const int tid = threadIdx.x, lane = tid & 63, wid = tid >> 6;
  const int bid = blockIdx.x;
  const int et = bid % 6, rt = bid / 6;       // e-tile fastest: A-tile reuse in cache
  const int l = rt >> 1, n0 = (rt & 1) << 7;
  const int wr = wid >> 1, wc = wid & 1;

  f32x4 acc[4][4] = {};

  const int rowA = lane >> 3;        // staging: 8 lanes/row, 16B each = 128B rows
  const int kkA = (lane & 7) * 8;

  for (int kt = 0; kt < 4; ++kt) {
    __syncthreads();
    const int k0 = kt * 64;
    for (int p = 0; p < 4; ++p) {
      const int chunk = p * 4 + wid;          // wave-uniform
      const int row = chunk * 8 + rowA;
      const unsigned short* gA = xb + (((size_t)(n0 + row)) * LS + l) * DS + k0 + kkA;
      gld16(gA, &As[chunk * 8 * 64]);
      const unsigned short* gB = wq + ((size_t)(et * 128 + row)) * DS + k0 + kkA;
      gld16(gB, &Bs[chunk * 8 * 64]);
    }
    __syncthreads();   // compiler drains vmcnt(0) here -> staged data visible
    for (int kf = 0; kf < 2; ++kf) {
      const int ko = kf * 32 + (lane >> 4) * 8;
      bf16x8 a[4], b[4];
      for (int m = 0; m < 4; ++m)
        a[m] = *(const bf16x8*)&As[(wr * 64 + m * 16 + (lane & 15)) * 64 + ko];
      for (int nn = 0; nn < 4; ++nn)
        b[nn] = *(const bf16x8*)&Bs[(wc * 64 + nn * 16 + (lane & 15)) * 64 + ko];
      for (int m = 0; m < 4; ++m)
        for (int nn = 0; nn < 4; ++nn)
          acc[m][nn] = mfma16(a[m], b[nn], acc[m][nn]);
    }
  }

  // Epilogue: C/D layout col=lane&15, row=(lane>>4)*4+j. Scatter to [which][h][l][n][hd].
  const int rbase = (lane >> 4) * 4, cbase = lane & 15;
  for (int m = 0; m < 4; ++m)
    for (int nn = 0; nn < 4; ++nn) {
      const int e = et * 128 + wc * 64 + nn * 16 + cbase;
      const int which = e >> 8, h = (e >> 5) & 7, d = e & 31;
      const size_t base = (((size_t)which * HS + h) * LS + l) * (NS * HD) + d;
      for (int j = 0; j < 4; ++j) {
        const int n = n0 + wr * 64 + m * 16 + rbase + j;
        qkv[base + (size_t)n * HD] = f2bf(acc[m][nn][j]);
      }
    }
}

// ---------------- attention over the sample axis ----------------
// One block per (h,l). 4 waves x 64 query rows. Flash loop over 4 key-blocks of 64.
__global__ __launch_bounds__(256) void k_attn(const unsigned short* __restrict__ qkv,
                                              const float* __restrict__ bias,
                                              unsigned short* __restrict__ att) {
  __shared__ unsigned short Vt[32][NS + 8];   // V transposed: B-operand of PV needs V^T[d][m]
  __shared__ unsigned short Pl[4][64][72];    // per-wave P tile (stride 72 -> 2-way = free)
  const int tid = threadIdx.x, lane = tid & 63, wid = tid >> 6;
  const int h = blockIdx.x >> 9, l = blockIdx.x & 511;
  const unsigned short* qb = qkv + (((size_t)0 * HS + h) * LS + l) * (NS * HD);
  const unsigned short* kb = qkv + (((size_t)1 * HS + h) * LS + l) * (NS * HD);
  const unsigned short* vb = qkv + (((size_t)2 * HS + h) * LS + l) * (NS * HD);

  // stage V^T (one row per thread, contiguous 128B runs per d column -> conflict-free)
  {
    const unsigned short* vr = vb + tid * HD;
    for (int c = 0; c < 4; ++c) {
      ushort8 v8 = *(const ushort8*)(vr + c * 8);
      for (int jj = 0; jj < 8; ++jj) Vt[c * 8 + jj][tid] = v8[jj];
    }
  }

  const int wbase = wid * 64, fr = lane & 15, fk = (lane >> 4) * 8;
  bf16x8 qf[4];
  for (int m = 0; m < 4; ++m)
    qf[m] = *(const bf16x8*)(qb + (size_t)(wbase + m * 16 + fr) * HD + fk);

  f32x4 o[4][2] = {};
  float mo[4][4], ls[4][4];
  for (int m = 0; m < 4; ++m)
    for (int j = 0; j < 4; ++j) { mo[m][j] = -1e30f; ls[m][j] = 0.f; }

  __syncthreads();

  for (int cb = 0; cb < 4; ++cb) {
    const int c0 = cb * 64;
    bf16x8 kfr[4];
    for (int nn = 0; nn < 4; ++nn)
      kfr[nn] = *(const bf16x8*)(kb + (size_t)(c0 + nn * 16 + fr) * HD + fk);
    f32x4 s[4][4];
    f32x4 z = {};
    for (int m = 0; m < 4; ++m)
      for (int nn = 0; nn < 4; ++nn)
        s[m][nn] = mfma16(qf[m], kfr[nn], z);

    // scale + bias, wave-parallel row max/sum (16-lane xor-shuffle), online softmax
    for (int m = 0; m < 4; ++m)
      for (int j = 0; j < 4; ++j) {
        const int row = wbase + m * 16 + (lane >> 4) * 4 + j;
        const float* brow = bias + (size_t)row * NS + c0 + fr;
        float mx = -1e30f;
        for (int nn = 0; nn < 4; ++nn) {
          float v = s[m][nn][j] * SCALE + brow[nn * 16];
          s[m][nn][j] = v;
          mx = fmaxf(mx, v);
        }
        for (int off = 1; off < 16; off <<= 1) mx = fmaxf(mx, __shfl_xor(mx, off));
        const float mn = fmaxf(mo[m][j], mx);
        const float f = __expf(mo[m][j] - mn);
        mo[m][j] = mn;
        float rs = 0.f;
        const int prow = m * 16 + (lane >> 4) * 4 + j;
        for (int nn = 0; nn < 4; ++nn) {
          float p = __expf(s[m][nn][j] - mn);
          rs += p;
          Pl[wid][prow][nn * 16 + fr] = f2bf(p);
        }
        for (int off = 1; off < 16; off <<= 1) rs += __shfl_xor(rs, off);
        ls[m][j] = ls[m][j] * f + rs;
        o[m][0][j] *= f;
        o[m][1][j] *= f;
      }

    // PV: A = P rows (LDS), B = V^T rows (LDS)
    for (int kf = 0; kf < 2; ++kf) {
      const int ko = kf * 32 + fk;
      bf16x8 pa[4], vv[2];
      for (int m = 0; m < 4; ++m)
        pa[m] = *(const bf16x8*)&Pl[wid][m * 16 + fr][ko];
      for (int df = 0; df < 2; ++df)
        vv[df] = *(const bf16x8*)&Vt[df * 16 + fr][c0 + ko];
      for (int m = 0; m < 4; ++m)
        for (int df = 0; df < 2; ++df)
          o[m][df] = mfma16(pa[m], vv[df], o[m][df]);
    }
  }

  // finalize: divide by l, write to [n][l][h*32+d] (proj-GEMM-friendly layout)
  for (int m = 0; m < 4; ++m)
    for (int j = 0; j < 4; ++j) {
      const float inv = 1.0f / ls[m][j];
      const int n = wbase + m * 16 + (lane >> 4) * 4 + j;
      const size_t ob = ((size_t)n * LS + l) * DS + h * HD;
      att[ob + 0 * 16 + fr] = f2bf(o[m][0][j] * inv);
      att[ob + 1 * 16 + fr] = f2bf(o[m][1][j] * inv);
    }
}

// ---------------- output projection GEMM (+bias, fp32 out) ----------------
__global__ __launch_bounds__(256) void k_proj(const unsigned short* __restrict__ ab,
                                              const unsigned short* __restrict__ wp,
                                              const float* __restrict__ bp,
                                              float* __restrict__ out) {
  __shared__ unsigned short As[128 * 64];
  __shared__ unsigned short Bs[128 * 64];
  const int tid = threadIdx.x, lane = tid & 63, wid = tid >> 6;
  const int bid = blockIdx.x;
  const int et = bid & 1, rt = bid >> 1;
  const int wr = wid >> 1, wc = wid & 1;

  f32x4 acc[4][4] = {};
  const int rowA = lane >> 3;
  const int kkA = (lane & 7) * 8;

  for (int kt = 0; kt < 4; ++kt) {
    __syncthreads();
    const int k0 = kt * 64;
    for (int p = 0; p < 4; ++p) {
      const int chunk = p * 4 + wid;
      const int row = chunk * 8 + rowA;
      const unsigned short* gA = ab + ((size_t)(rt * 128 + row)) * DS + k0 + kkA;
      gld16(gA, &As[chunk * 8 * 64]);
      const unsigned short* gB = wp + ((size_t)(et * 128 + row)) * DS + k0 + kkA;
      gld16(gB, &Bs[chunk * 8 * 64]);
    }
    __syncthreads();
    for (int kf = 0; kf < 2; ++kf) {
      const int ko = kf * 32 + (lane >> 4) * 8;
      bf16x8 a[4], b[4];
      for (int m = 0; m < 4; ++m)
        a[m] = *(const bf16x8*)&As[(wr * 64 + m * 16 + (lane & 15)) * 64 + ko];
      for (int nn = 0; nn < 4; ++nn)
        b[nn] = *(const bf16x8*)&Bs[(wc * 64 + nn * 16 + (lane & 15)) * 64 + ko];
      for (int m = 0; m < 4; ++m)
        for (int nn = 0; nn < 4; ++nn)
          acc[m][nn] = mfma16(a[m], b[nn], acc[m][nn]);
    }
  }

  const int rbase = (lane >> 4) * 4, cbase = lane & 15;
  for (int m = 0; m < 4; ++m)
    for (int nn = 0; nn < 4; ++nn) {
      const int e = et * 128 + wc * 64 + nn * 16 + cbase;
      const float bv = bp[e];
      for (int j = 0; j < 4; ++j) {
        const size_t mm = (size_t)rt * 128 + wr * 64 + m * 16 + rbase + j;
        out[mm * DS + e] = acc[m][nn][j] + bv;
      }
    }
}

extern "C" void kernel_launch(void* const* d_in, const int* in_sizes, int n_in,
                              void* d_out, int out_size, void* d_ws, size_t ws_size,
                              hipStream_t stream) {
  const float* x     = (const float*)d_in[0];  // (256,512,256)
  const float* dist  = (const float*)d_in[1];  // (256,256)
  const float* wqkv  = (const float*)d_in[2];  // (768,256)
  const float* wproj = (const float*)d_in[3];  // (256,256)
  const float* bproj = (const float*)d_in[4];  // (256,)
  float* out = (float*)d_out;

  // ws layout (ushort elements; total 336 MB):
  unsigned short* ws   = (unsigned short*)d_ws;
  unsigned short* xb   = ws;                    // 33,554,432  x as bf16 [n][l][d]
  unsigned short* wqb  = xb + 33554432;         // 196,608     w_qkv bf16
  unsigned short* wpb  = wqb + 196608;          // 65,536      w_proj bf16
  unsigned short* qkvb = wpb + 65536;           // 100,663,296 [3][h][l][n][hd] bf16
  unsigned short* attb = qkvb + 100663296;      // 33,554,432  attn out [n][l][h*hd+d] bf16

  k_cvt<<<8192, 256, 0, stream>>>(x, xb, 33554432);
  k_cvt<<<96, 256, 0, stream>>>(wqkv, wqb, 196608);
  k_cvt<<<32, 256, 0, stream>>>(wproj, wpb, 65536);
  k_qkv<<<6144, 256, 0, stream>>>(xb, wqb, qkvb);
  k_attn<<<4096, 256, 0, stream>>>(qkvb, dist, attb);
  k_proj<<<2048, 256, 0, stream>>>(attb, wpb, bproj, out);
}

// Round 2
// 665.626 us; speedup vs baseline: 1.0672x; 1.0672x over previous
//
#include <hip/hip_runtime.h>
#include <stdint.h>

// Problem constants (from reference): x (N,L,D), attention over sample axis N.
#define NS 256
#define LS 512
#define DS 256
#define HS 8
#define HD 32
#define SCALE 0.17677669529663687f   // hd^-0.5
#define LOG2E 1.4426950408889634f
#define QSCALE (SCALE * LOG2E)       // folded into Q at projection time

typedef __attribute__((ext_vector_type(4))) float f32x4;
typedef __attribute__((ext_vector_type(8))) __bf16 bf16x8;
typedef __attribute__((ext_vector_type(8))) unsigned short ushort8;

// fp32 -> bf16 round-to-nearest-even (finite inputs only)
static __device__ __forceinline__ unsigned short f2bf(float f) {
  unsigned int u = __builtin_bit_cast(unsigned int, f);
  u += 0x7fffu + ((u >> 16) & 1u);
  return (unsigned short)(u >> 16);
}

// async global->LDS, 16B per lane. LDS dest is wave-uniform base + lane*16.
static __device__ __forceinline__ void gld16(const void* g, void* l) {
  __builtin_amdgcn_global_load_lds((const __attribute__((address_space(1))) void*)g,
                                   (__attribute__((address_space(3))) void*)l, 16, 0, 0);
}

static __device__ __forceinline__ f32x4 mfma16(bf16x8 a, bf16x8 b, f32x4 c) {
  return __builtin_amdgcn_mfma_f32_16x16x32_bf16(a, b, c, 0, 0, 0);
}

// ---------------- fp32 -> bf16 conversion (vectorized, grid-stride) ----------------
__global__ void k_cvt(const float* __restrict__ in, unsigned short* __restrict__ out, int n) {
  int stride = gridDim.x * blockDim.x;
  for (int i = blockIdx.x * blockDim.x + threadIdx.x; i * 8 < n; i += stride) {
    int b = i * 8;
    float4 a0 = *(const float4*)(in + b);
    float4 a1 = *(const float4*)(in + b + 4);
    ushort8 o;
    o[0] = f2bf(a0.x); o[1] = f2bf(a0.y); o[2] = f2bf(a0.z); o[3] = f2bf(a0.w);
    o[4] = f2bf(a1.x); o[5] = f2bf(a1.y); o[6] = f2bf(a1.z); o[7] = f2bf(a1.w);
    *(ushort8*)(out + b) = o;
  }
}

// ---------------- bias transpose + log2e prescale: bT[col][row] = dist[row][col]*LOG2E ----
__global__ void k_bt(const float* __restrict__ d, float* __restrict__ bT) {
  int i = blockIdx.x * 256 + threadIdx.x;          // 65536 elements
  int r = i >> 8, c = i & 255;
  bT[(size_t)c * NS + r] = d[i] * LOG2E;
}

// ---------------- QKV projection GEMM ----------------
// C[r][e] = sum_d x_row(r)[d] * w_qkv[e][d]; Q part (e<256) pre-scaled by QSCALE.
__global__ __launch_bounds__(256) void k_qkv(const unsigned short* __restrict__ xb,
                                             const unsigned short* __restrict__ wq,
                                             unsigned short* __restrict__ qkv) {
  __shared__ unsigned short As[128 * 64];
  __shared__ unsigned short Bs[128 * 64];
  const int tid = threadIdx.x, lane = tid & 63, wid = tid >> 6;
  const int bid = blockIdx.x;
  const int et = bid % 6, rt = bid / 6;
  const int l = rt >> 1, n0 = (rt & 1) << 7;
  const int wr = wid >> 1, wc = wid & 1;

  f32x4 acc[4][4] = {};
  const int rowA = lane >> 3;
  const int kkA = (lane & 7) * 8;

  for (int kt = 0; kt < 4; ++kt) {
    __syncthreads();
    const int k0 = kt * 64;
    for (int p = 0; p < 4; ++p) {
      const int chunk = p * 4 + wid;
      const int row = chunk * 8 + rowA;
      const unsigned short* gA = xb + (((size_t)(n0 + row)) * LS + l) * DS + k0 + kkA;
      gld16(gA, &As[chunk * 8 * 64]);
      const unsigned short* gB = wq + ((size_t)(et * 128 + row)) * DS + k0 + kkA;
      gld16(gB, &Bs[chunk * 8 * 64]);
    }
    __syncthreads();
    for (int kf = 0; kf < 2; ++kf) {
      const int ko = kf * 32 + (lane >> 4) * 8;
      bf16x8 a[4], b[4];
      for (int m = 0; m < 4; ++m)
        a[m] = *(const bf16x8*)&As[(wr * 64 + m * 16 + (lane & 15)) * 64 + ko];
      for (int nn = 0; nn < 4; ++nn)
        b[nn] = *(const bf16x8*)&Bs[(wc * 64 + nn * 16 + (lane & 15)) * 64 + ko];
      for (int m = 0; m < 4; ++m)
        for (int nn = 0; nn < 4; ++nn)
          acc[m][nn] = mfma16(a[m], b[nn], acc[m][nn]);
    }
  }

  const int rbase = (lane >> 4) * 4, cbase = lane & 15;
  for (int m = 0; m < 4; ++m)
    for (int nn = 0; nn < 4; ++nn) {
      const int e = et * 128 + wc * 64 + nn * 16 + cbase;
      const int which = e >> 8, h = (e >> 5) & 7, d = e & 31;
      const float qs = (which == 0) ? QSCALE : 1.0f;
      const size_t base = (((size_t)which * HS + h) * LS + l) * (NS * HD) + d;
      for (int j = 0; j < 4; ++j) {
        const int n = n0 + wr * 64 + m * 16 + rbase + j;
        qkv[base + (size_t)n * HD] = f2bf(acc[m][nn][j] * qs);
      }
    }
}

// ---------------- attention over the sample axis ----------------
// One block per (h,l). 4 waves x 64 query rows. Flash loop over 4 key-blocks of 64.
// Per m-subtile: QK (4 MFMA) -> softmax of 16 rows (base-2, bias added inside exp)
// -> PV (4 MFMA). Pl is a per-wave 16-row transpose buffer (LDS total 26.1 KB).
__global__ __launch_bounds__(256) void k_attn(const unsigned short* __restrict__ qkv,
                                              const float* __restrict__ bT,
                                              unsigned short* __restrict__ att) {
  __shared__ unsigned short Vt[32][NS + 8];    // V^T, stride 528B (16B-mult, banks balanced)
  __shared__ unsigned short Pl[4][16][72];     // per-wave P transpose tile, stride 144B
  const int tid = threadIdx.x, lane = tid & 63, wid = tid >> 6;
  const int h = blockIdx.x >> 9, l = blockIdx.x & 511;
  const unsigned short* qb = qkv + (((size_t)0 * HS + h) * LS + l) * (NS * HD);
  const unsigned short* kb = qkv + (((size_t)1 * HS + h) * LS + l) * (NS * HD);
  const unsigned short* vb = qkv + (((size_t)2 * HS + h) * LS + l) * (NS * HD);

  // stage V^T
  {
    const unsigned short* vr = vb + tid * HD;
    for (int c = 0; c < 4; ++c) {
      ushort8 v8 = *(const ushort8*)(vr + c * 8);
      for (int jj = 0; jj < 8; ++jj) Vt[c * 8 + jj][tid] = v8[jj];
    }
  }

  const int wbase = wid * 64, fr = lane & 15, g = lane >> 4, fk = g * 8;
  bf16x8 qf[4];
#pragma unroll
  for (int m = 0; m < 4; ++m)
    qf[m] = *(const bf16x8*)(qb + (size_t)(wbase + m * 16 + fr) * HD + fk);

  f32x4 o[4][2] = {};
  float mo[4][4], ls[4][4];
#pragma unroll
  for (int m = 0; m < 4; ++m)
#pragma unroll
    for (int j = 0; j < 4; ++j) { mo[m][j] = -1e30f; ls[m][j] = 0.f; }

  __syncthreads();

  for (int cb = 0; cb < 4; ++cb) {
    const int c0 = cb * 64;
    bf16x8 kfr[4];
#pragma unroll
    for (int nn = 0; nn < 4; ++nn)
      kfr[nn] = *(const bf16x8*)(kb + (size_t)(c0 + nn * 16 + fr) * HD + fk);

#pragma unroll
    for (int m = 0; m < 4; ++m) {
      // bias fragments (transposed layout -> one float4 per (m,nn)), issued early
      float4 bfv[4];
#pragma unroll
      for (int nn = 0; nn < 4; ++nn)
        bfv[nn] = *(const float4*)(bT + (size_t)(c0 + nn * 16 + fr) * NS + wbase + m * 16 + g * 4);

      f32x4 z = {};
      f32x4 s[4];
#pragma unroll
      for (int nn = 0; nn < 4; ++nn) s[nn] = mfma16(qf[m], kfr[nn], z);

#pragma unroll
      for (int j = 0; j < 4; ++j) {
        float mx = fmaxf(fmaxf(s[0][j], s[1][j]), fmaxf(s[2][j], s[3][j]));
#pragma unroll
        for (int off = 1; off < 16; off <<= 1) mx = fmaxf(mx, __shfl_xor(mx, off));
        const float mn = fmaxf(mo[m][j], mx);
        const float f = __builtin_exp2f(mo[m][j] - mn);
        mo[m][j] = mn;
        float rs = 0.f;
#pragma unroll
        for (int nn = 0; nn < 4; ++nn) {
          const float bj = (j == 0) ? bfv[nn].x : (j == 1) ? bfv[nn].y
                         : (j == 2) ? bfv[nn].z : bfv[nn].w;
          float p = __builtin_exp2f(s[nn][j] - mn + bj);
          rs += p;
          Pl[wid][g * 4 + j][nn * 16 + fr] = f2bf(p);
        }
#pragma unroll
        for (int off = 1; off < 16; off <<= 1) rs += __shfl_xor(rs, off);
        ls[m][j] = ls[m][j] * f + rs;
        o[m][0][j] *= f;
        o[m][1][j] *= f;
      }

      // PV for this m-subtile (same wave wrote Pl; compiler inserts lgkmcnt waits)
#pragma unroll
      for (int kf = 0; kf < 2; ++kf) {
        const int ko = kf * 32 + fk;
        bf16x8 pa = *(const bf16x8*)&Pl[wid][fr][ko];
#pragma unroll
        for (int df = 0; df < 2; ++df) {
          bf16x8 vv = *(const bf16x8*)&Vt[df * 16 + fr][c0 + ko];
          o[m][df] = mfma16(pa, vv, o[m][df]);
        }
      }
    }
  }

  // finalize: divide by ls, write to [n][l][h*32+d] (proj-GEMM-friendly layout)
#pragma unroll
  for (int m = 0; m < 4; ++m)
#pragma unroll
    for (int j = 0; j < 4; ++j) {
      const float inv = 1.0f / ls[m][j];
      const int n = wbase + m * 16 + g * 4 + j;
      const size_t ob = ((size_t)n * LS + l) * DS + h * HD;
      att[ob + 0 * 16 + fr] = f2bf(o[m][0][j] * inv);
      att[ob + 1 * 16 + fr] = f2bf(o[m][1][j] * inv);
    }
}

// ---------------- output projection GEMM (+bias, fp32 out) ----------------
__global__ __launch_bounds__(256) void k_proj(const unsigned short* __restrict__ ab,
                                              const unsigned short* __restrict__ wp,
                                              const float* __restrict__ bp,
                                              float* __restrict__ out) {
  __shared__ unsigned short As[128 * 64];
  __shared__ unsigned short Bs[128 * 64];
  const int tid = threadIdx.x, lane = tid & 63, wid = tid >> 6;
  const int bid = blockIdx.x;
  const int et = bid & 1, rt = bid >> 1;
  const int wr = wid >> 1, wc = wid & 1;

  f32x4 acc[4][4] = {};
  const int rowA = lane >> 3;
  const int kkA = (lane & 7) * 8;

  for (int kt = 0; kt < 4; ++kt) {
    __syncthreads();
    const int k0 = kt * 64;
    for (int p = 0; p < 4; ++p) {
      const int chunk = p * 4 + wid;
      const int row = chunk * 8 + rowA;
      const unsigned short* gA = ab + ((size_t)(rt * 128 + row)) * DS + k0 + kkA;
      gld16(gA, &As[chunk * 8 * 64]);
      const unsigned short* gB = wp + ((size_t)(et * 128 + row)) * DS + k0 + kkA;
      gld16(gB, &Bs[chunk * 8 * 64]);
    }
    __syncthreads();
    for (int kf = 0; kf < 2; ++kf) {
      const int ko = kf * 32 + (lane >> 4) * 8;
      bf16x8 a[4], b[4];
      for (int m = 0; m < 4; ++m)
        a[m] = *(const bf16x8*)&As[(wr * 64 + m * 16 + (lane & 15)) * 64 + ko];
      for (int nn = 0; nn < 4; ++nn)
        b[nn] = *(const bf16x8*)&Bs[(wc * 64 + nn * 16 + (lane & 15)) * 64 + ko];
      for (int m = 0; m < 4; ++m)
        for (int nn = 0; nn < 4; ++nn)
          acc[m][nn] = mfma16(a[m], b[nn], acc[m][nn]);
    }
  }

  const int rbase = (lane >> 4) * 4, cbase = lane & 15;
  for (int m = 0; m < 4; ++m)
    for (int nn = 0; nn < 4; ++nn) {
      const int e = et * 128 + wc * 64 + nn * 16 + cbase;
      const float bv = bp[e];
      for (int j = 0; j < 4; ++j) {
        const size_t mm = (size_t)rt * 128 + wr * 64 + m * 16 + rbase + j;
        out[mm * DS + e] = acc[m][nn][j] + bv;
      }
    }
}

extern "C" void kernel_launch(void* const* d_in, const int* in_sizes, int n_in,
                              void* d_out, int out_size, void* d_ws, size_t ws_size,
                              hipStream_t stream) {
  const float* x     = (const float*)d_in[0];  // (256,512,256)
  const float* dist  = (const float*)d_in[1];  // (256,256)
  const float* wqkv  = (const float*)d_in[2];  // (768,256)
  const float* wproj = (const float*)d_in[3];  // (256,256)
  const float* bproj = (const float*)d_in[4];  // (256,)
  float* out = (float*)d_out;

  // ws layout (ushort elements):
  unsigned short* ws   = (unsigned short*)d_ws;
  unsigned short* xb   = ws;                    // 33,554,432  x as bf16 [n][l][d]
  unsigned short* wqb  = xb + 33554432;         // 196,608     w_qkv bf16
  unsigned short* wpb  = wqb + 196608;          // 65,536      w_proj bf16
  unsigned short* qkvb = wpb + 65536;           // 100,663,296 [3][h][l][n][hd] bf16
  unsigned short* attb = qkvb + 100663296;      // 33,554,432  attn out bf16
  float* bTf           = (float*)(attb + 33554432); // 65,536 f32: bias^T * log2e

  k_cvt<<<8192, 256, 0, stream>>>(x, xb, 33554432);
  k_cvt<<<96, 256, 0, stream>>>(wqkv, wqb, 196608);
  k_cvt<<<32, 256, 0, stream>>>(wproj, wpb, 65536);
  k_bt<<<256, 256, 0, stream>>>(dist, bTf);
  k_qkv<<<6144, 256, 0, stream>>>(xb, wqb, qkvb);
  k_attn<<<4096, 256, 0, stream>>>(qkvb, bTf, attb);
  k_proj<<<2048, 256, 0, stream>>>(attb, wpb, bproj, out);
}

// Round 9
// 562.634 us; speedup vs baseline: 1.2626x; 1.1831x over previous
//
#include <hip/hip_runtime.h>
#include <stdint.h>

// Problem constants (from reference): x (N,L,D), attention over the sample axis N.
#define NS 256
#define LS 512
#define DS 256
#define HS 8
#define HD 32
#define SCALE 0.17677669529663687f   // hd^-0.5
#define LOG2E 1.4426950408889634f
#define QSCALE (SCALE * LOG2E)       // folded into Q at projection time

typedef __attribute__((ext_vector_type(4))) float f32x4;
typedef __attribute__((ext_vector_type(8))) __bf16 bf16x8;
typedef __attribute__((ext_vector_type(4))) __bf16 bf16x4;
typedef __attribute__((ext_vector_type(8))) unsigned short ushort8;

// fp32 -> bf16 round-to-nearest-even (finite inputs only)
static __device__ __forceinline__ unsigned short f2bf(float f) {
  unsigned int u = __builtin_bit_cast(unsigned int, f);
  u += 0x7fffu + ((u >> 16) & 1u);
  return (unsigned short)(u >> 16);
}

// async global->LDS, 16B per lane. LDS dest is wave-uniform base + lane*16.
static __device__ __forceinline__ void gld16(const void* g, void* l) {
  __builtin_amdgcn_global_load_lds((const __attribute__((address_space(1))) void*)g,
                                   (__attribute__((address_space(3))) void*)l, 16, 0, 0);
}

static __device__ __forceinline__ f32x4 mfma16(bf16x8 a, bf16x8 b, f32x4 c) {
  return __builtin_amdgcn_mfma_f32_16x16x32_bf16(a, b, c, 0, 0, 0);
}

// ---------------- fp32 -> bf16 conversion (vectorized, grid-stride) ----------------
__global__ void k_cvt(const float* __restrict__ in, unsigned short* __restrict__ out, int n) {
  int stride = gridDim.x * blockDim.x;
  for (int i = blockIdx.x * blockDim.x + threadIdx.x; i * 8 < n; i += stride) {
    int b = i * 8;
    float4 a0 = *(const float4*)(in + b);
    float4 a1 = *(const float4*)(in + b + 4);
    ushort8 o;
    o[0] = f2bf(a0.x); o[1] = f2bf(a0.y); o[2] = f2bf(a0.z); o[3] = f2bf(a0.w);
    o[4] = f2bf(a1.x); o[5] = f2bf(a1.y); o[6] = f2bf(a1.z); o[7] = f2bf(a1.w);
    *(ushort8*)(out + b) = o;
  }
}

// ---------------- QKV projection GEMM ----------------
// C[r][e] = sum_d x_row(r)[d] * w_qkv[e][d]; Q part (e<256) pre-scaled by QSCALE.
__global__ __launch_bounds__(256) void k_qkv(const unsigned short* __restrict__ xb,
                                             const unsigned short* __restrict__ wq,
                                             unsigned short* __restrict__ qkv) {
  __shared__ unsigned short As[128 * 64];
  __shared__ unsigned short Bs[128 * 64];
  const int tid = threadIdx.x, lane = tid & 63, wid = tid >> 6;
  const int bid = blockIdx.x;
  const int et = bid % 6, rt = bid / 6;
  const int l = rt >> 1, n0 = (rt & 1) << 7;
  const int wr = wid >> 1, wc = wid & 1;

  f32x4 acc[4][4] = {};
  const int rowA = lane >> 3;
  const int kkA = (lane & 7) * 8;

  for (int kt = 0; kt < 4; ++kt) {
    __syncthreads();
    const int k0 = kt * 64;
    for (int p = 0; p < 4; ++p) {
      const int chunk = p * 4 + wid;
      const int row = chunk * 8 + rowA;
      const unsigned short* gA = xb + (((size_t)(n0 + row)) * LS + l) * DS + k0 + kkA;
      gld16(gA, &As[chunk * 8 * 64]);
      const unsigned short* gB = wq + ((size_t)(et * 128 + row)) * DS + k0 + kkA;
      gld16(gB, &Bs[chunk * 8 * 64]);
    }
    __syncthreads();
    for (int kf = 0; kf < 2; ++kf) {
      const int ko = kf * 32 + (lane >> 4) * 8;
      bf16x8 a[4], b[4];
      for (int m = 0; m < 4; ++m)
        a[m] = *(const bf16x8*)&As[(wr * 64 + m * 16 + (lane & 15)) * 64 + ko];
      for (int nn = 0; nn < 4; ++nn)
        b[nn] = *(const bf16x8*)&Bs[(wc * 64 + nn * 16 + (lane & 15)) * 64 + ko];
      for (int m = 0; m < 4; ++m)
        for (int nn = 0; nn < 4; ++nn)
          acc[m][nn] = mfma16(a[m], b[nn], acc[m][nn]);
    }
  }

  const int rbase = (lane >> 4) * 4, cbase = lane & 15;
  for (int m = 0; m < 4; ++m)
    for (int nn = 0; nn < 4; ++nn) {
      const int e = et * 128 + wc * 64 + nn * 16 + cbase;
      const int which = e >> 8, h = (e >> 5) & 7, d = e & 31;
      const float qs = (which == 0) ? QSCALE : 1.0f;
      const size_t base = (((size_t)which * HS + h) * LS + l) * (NS * HD) + d;
      for (int j = 0; j < 4; ++j) {
        const int n = n0 + wr * 64 + m * 16 + rbase + j;
        qkv[base + (size_t)n * HD] = f2bf(acc[m][nn][j] * qs);
      }
    }
}

// ---------------- attention over the sample axis (swapped-QK lane-local softmax) -------
// 2 blocks per (h,l); each block: 4 waves x 32 q-rows. Flash loop over 4 key-blocks
// of 64. QK^T computed as mfma(K,Q) so D[k][q]: lane owns one q (=lane&15) with 16
// k-values in registers -> row softmax is in-register + 2 shuffles. P repacked to
// PV A-fragment layout via per-wave LDS tile (conflict-free stride 68).
__global__ __launch_bounds__(256, 4) void k_attn(const unsigned short* __restrict__ qkv,
                                                 const float* __restrict__ dist,
                                                 unsigned short* __restrict__ att) {
  __shared__ unsigned short Vt[32][NS + 8];   // V^T [d][k]
  __shared__ __bf16 Pl[4][16][68];            // per-wave P [q][k] tile
  const int tid = threadIdx.x, lane = tid & 63, wid = tid >> 6;
  const int bid = blockIdx.x;
  const int h = bid >> 10, l = (bid >> 1) & 511, half = bid & 1;
  const int n0 = half << 7;
  const unsigned short* qb = qkv + (((size_t)0 * HS + h) * LS + l) * (NS * HD);
  const unsigned short* kb = qkv + (((size_t)1 * HS + h) * LS + l) * (NS * HD);
  const unsigned short* vb = qkv + (((size_t)2 * HS + h) * LS + l) * (NS * HD);

  // stage V^T (all 256 k-rows; both half-blocks need all keys)
  {
    const unsigned short* vr = vb + tid * HD;
    for (int c = 0; c < 4; ++c) {
      ushort8 v8 = *(const ushort8*)(vr + c * 8);
      for (int jj = 0; jj < 8; ++jj) Vt[c * 8 + jj][tid] = v8[jj];
    }
  }

  const int fr = lane & 15, g = lane >> 4, fk = g * 8;
  const int wq0 = n0 + wid * 32;
  bf16x8 qf[2];
#pragma unroll
  for (int m = 0; m < 2; ++m)
    qf[m] = *(const bf16x8*)(qb + (size_t)(wq0 + m * 16 + fr) * HD + fk);

  f32x4 o[2][2] = {};
  float mo[2] = {-1e30f, -1e30f}, ls[2] = {0.f, 0.f};

  __syncthreads();

  for (int cb = 0; cb < 4; ++cb) {
    const int c0 = cb * 64;
    bf16x8 kfr[4];
#pragma unroll
    for (int nn = 0; nn < 4; ++nn)
      kfr[nn] = *(const bf16x8*)(kb + (size_t)(c0 + nn * 16 + fr) * HD + fk);

#pragma unroll
    for (int m = 0; m < 2; ++m) {
      const int qg = wq0 + m * 16 + fr;     // this lane's q row
      // bias fragments: contiguous float4 from the ORIGINAL dist layout
      float4 bv[4];
#pragma unroll
      for (int nn = 0; nn < 4; ++nn)
        bv[nn] = *(const float4*)(dist + (size_t)qg * NS + c0 + nn * 16 + g * 4);

      f32x4 z = {};
      f32x4 s[4];
#pragma unroll
      for (int nn = 0; nn < 4; ++nn) s[nn] = mfma16(kfr[nn], qf[m], z);

      // bias*log2e + max over this lane's 16 k-values, then 2-shuffle reduce
      float mx = -1e30f;
#pragma unroll
      for (int nn = 0; nn < 4; ++nn) {
#pragma unroll
        for (int j = 0; j < 4; ++j) {
          const float b = (j == 0) ? bv[nn].x : (j == 1) ? bv[nn].y
                        : (j == 2) ? bv[nn].z : bv[nn].w;
          const float v = fmaf(b, LOG2E, s[nn][j]);
          s[nn][j] = v;
          mx = fmaxf(mx, v);
        }
      }
      mx = fmaxf(mx, __shfl_xor(mx, 16));
      mx = fmaxf(mx, __shfl_xor(mx, 32));
      const float mn = fmaxf(mo[m], mx);
      const float fsc = __builtin_exp2f(mo[m] - mn);
      mo[m] = mn;

      float rs = 0.f;
#pragma unroll
      for (int nn = 0; nn < 4; ++nn) {
        bf16x4 pk;
#pragma unroll
        for (int j = 0; j < 4; ++j) {
          const float p = __builtin_exp2f(s[nn][j] - mn);
          rs += p;
          pk[j] = (__bf16)p;
        }
        *(bf16x4*)&Pl[wid][fr][nn * 16 + g * 4] = pk;   // ds_write_b64, conflict-free
      }
      rs += __shfl_xor(rs, 16);
      rs += __shfl_xor(rs, 32);
      ls[m] = ls[m] * fsc + rs;

      // rescale o (broadcast fsc from the lane owning each o-row's q)
#pragma unroll
      for (int j = 0; j < 4; ++j) {
        const float fo = __shfl(fsc, g * 4 + j);
        o[m][0][j] *= fo;
        o[m][1][j] *= fo;
      }

      // PV: A = P rows (LDS, same wave), B = V^T rows
#pragma unroll
      for (int kf = 0; kf < 2; ++kf) {
        const int ko = kf * 32 + fk;
        bf16x8 pa = *(const bf16x8*)&Pl[wid][fr][ko];   // ds_read_b128, conflict-free
#pragma unroll
        for (int df = 0; df < 2; ++df) {
          bf16x8 vv = *(const bf16x8*)&Vt[df * 16 + fr][c0 + ko];
          o[m][df] = mfma16(pa, vv, o[m][df]);
        }
      }
    }
  }

  // finalize: divide by ls (broadcast per o-row), write [n][l][h*32+d]
#pragma unroll
  for (int m = 0; m < 2; ++m) {
    const float inv = 1.0f / ls[m];
#pragma unroll
    for (int j = 0; j < 4; ++j) {
      const float invo = __shfl(inv, g * 4 + j);
      const int n = wq0 + m * 16 + g * 4 + j;
      const size_t ob = ((size_t)n * LS + l) * DS + h * HD;
      att[ob + 0 * 16 + fr] = f2bf(o[m][0][j] * invo);
      att[ob + 1 * 16 + fr] = f2bf(o[m][1][j] * invo);
    }
  }
}

// ---------------- output projection GEMM (+bias, fp32 out) ----------------
__global__ __launch_bounds__(256) void k_proj(const unsigned short* __restrict__ ab,
                                              const unsigned short* __restrict__ wp,
                                              const float* __restrict__ bp,
                                              float* __restrict__ out) {
  __shared__ unsigned short As[128 * 64];
  __shared__ unsigned short Bs[128 * 64];
  const int tid = threadIdx.x, lane = tid & 63, wid = tid >> 6;
  const int bid = blockIdx.x;
  const int et = bid & 1, rt = bid >> 1;
  const int wr = wid >> 1, wc = wid & 1;

  f32x4 acc[4][4] = {};
  const int rowA = lane >> 3;
  const int kkA = (lane & 7) * 8;

  for (int kt = 0; kt < 4; ++kt) {
    __syncthreads();
    const int k0 = kt * 64;
    for (int p = 0; p < 4; ++p) {
      const int chunk = p * 4 + wid;
      const int row = chunk * 8 + rowA;
      const unsigned short* gA = ab + ((size_t)(rt * 128 + row)) * DS + k0 + kkA;
      gld16(gA, &As[chunk * 8 * 64]);
      const unsigned short* gB = wp + ((size_t)(et * 128 + row)) * DS + k0 + kkA;
      gld16(gB, &Bs[chunk * 8 * 64]);
    }
    __syncthreads();
    for (int kf = 0; kf < 2; ++kf) {
      const int ko = kf * 32 + (lane >> 4) * 8;
      bf16x8 a[4], b[4];
      for (int m = 0; m < 4; ++m)
        a[m] = *(const bf16x8*)&As[(wr * 64 + m * 16 + (lane & 15)) * 64 + ko];
      for (int nn = 0; nn < 4; ++nn)
        b[nn] = *(const bf16x8*)&Bs[(wc * 64 + nn * 16 + (lane & 15)) * 64 + ko];
      for (int m = 0; m < 4; ++m)
        for (int nn = 0; nn < 4; ++nn)
          acc[m][nn] = mfma16(a[m], b[nn], acc[m][nn]);
    }
  }

  const int rbase = (lane >> 4) * 4, cbase = lane & 15;
  for (int m = 0; m < 4; ++m)
    for (int nn = 0; nn < 4; ++nn) {
      const int e = et * 128 + wc * 64 + nn * 16 + cbase;
      const float bv = bp[e];
      for (int j = 0; j < 4; ++j) {
        const size_t mm = (size_t)rt * 128 + wr * 64 + m * 16 + rbase + j;
        out[mm * DS + e] = acc[m][nn][j] + bv;
      }
    }
}

extern "C" void kernel_launch(void* const* d_in, const int* in_sizes, int n_in,
                              void* d_out, int out_size, void* d_ws, size_t ws_size,
                              hipStream_t stream) {
  const float* x     = (const float*)d_in[0];  // (256,512,256)
  const float* dist  = (const float*)d_in[1];  // (256,256)
  const float* wqkv  = (const float*)d_in[2];  // (768,256)
  const float* wproj = (const float*)d_in[3];  // (256,256)
  const float* bproj = (const float*)d_in[4];  // (256,)
  float* out = (float*)d_out;

  // ws layout (ushort elements):
  unsigned short* ws   = (unsigned short*)d_ws;
  unsigned short* xb   = ws;                    // 33,554,432  x as bf16 [n][l][d]
  unsigned short* wqb  = xb + 33554432;         // 196,608     w_qkv bf16
  unsigned short* wpb  = wqb + 196608;          // 65,536      w_proj bf16
  unsigned short* qkvb = wpb + 65536;           // 100,663,296 [3][h][l][n][hd] bf16
  unsigned short* attb = qkvb + 100663296;      // 33,554,432  attn out bf16

  k_cvt<<<8192, 256, 0, stream>>>(x, xb, 33554432);
  k_cvt<<<96, 256, 0, stream>>>(wqkv, wqb, 196608);
  k_cvt<<<32, 256, 0, stream>>>(wproj, wpb, 65536);
  k_qkv<<<6144, 256, 0, stream>>>(xb, wqb, qkvb);
  k_attn<<<8192, 256, 0, stream>>>(qkvb, dist, attb);
  k_proj<<<2048, 256, 0, stream>>>(attb, wpb, bproj, out);
}